// Round 16
// baseline (620.463 us; speedup 1.0000x reference)
//
#include <hip/hip_runtime.h>
#include <hip/hip_bf16.h>

#define T_TOKENS 8192
#define D_DIM 1024
#define H_DIM 4096
#define E_NUM 8
#define CAP 8192
#define CNT_PAD 16

#define TPB_G 32
#define GATE_BLKS (T_TOKENS / TPB_G)
#define TRW1_BLKS ((D_DIM / 64) * (H_DIM / 64) * E_NUM)
#define TRW2_BLKS ((H_DIM / 64) * (D_DIM / 64) * E_NUM)

typedef short bf16x8 __attribute__((ext_vector_type(8)));
typedef float f32x4 __attribute__((ext_vector_type(4)));
typedef unsigned short u16x8 __attribute__((ext_vector_type(8)));

__device__ inline unsigned short f2bf(float f) {
    __hip_bfloat16 h = __float2bfloat16(f);
    return *reinterpret_cast<unsigned short*>(&h);
}

__device__ inline float gelu_sig(float v) {
    float x = v * (1.5957691216057308f + 0.07135481627f * v * v);
    return v * __builtin_amdgcn_rcpf(1.0f + __expf(-x));
}

__device__ inline void gld_lds16(const unsigned short* g, unsigned short* lds) {
    __builtin_amdgcn_global_load_lds(
        (const __attribute__((address_space(1))) void*)g,
        (__attribute__((address_space(3))) void*)lds, 16, 0, 0);
}

#define WAITV0 do { asm volatile("s_waitcnt vmcnt(0)" ::: "memory"); \
                    __builtin_amdgcn_sched_barrier(0); } while (0)
#define LGKM0  do { asm volatile("s_waitcnt lgkmcnt(0)" ::: "memory"); \
                    __builtin_amdgcn_sched_barrier(0); } while (0)
#define SBAR   do { __builtin_amdgcn_sched_barrier(0); \
                    __builtin_amdgcn_s_barrier(); \
                    __builtin_amdgcn_sched_barrier(0); } while (0)

#define XCD_ITEMS(T)                                                          \
    int xcd = blockIdx.x & 7;                                                 \
    int lb  = blockIdx.x >> 3;                                                \
    int nbx = gridDim.x >> 3;                                                 \
    int q_ = (T) >> 3, r_ = (T) & 7;                                          \
    int base_ = (xcd < r_) ? xcd * (q_ + 1) : r_ * (q_ + 1) + (xcd - r_) * q_;\
    int cntx_ = (xcd < r_) ? q_ + 1 : q_;

// ---------------- fused prepass: gate(+x cvt) | trw(w1) | trw(w2) ----------
__device__ inline void trw_body(const float* __restrict__ w,
                                unsigned short* __restrict__ wt,
                                int K, int N, int bb,
                                unsigned short (*tb)[72]) {
    int nk = K / 64, nn = N / 64;
    int e = bb / (nk * nn);
    int rem = bb - e * (nk * nn);
    int k0 = (rem % nk) * 64;
    int n0 = (rem / nk) * 64;
    const float* we = w + (size_t)e * K * N + (size_t)k0 * N + n0;
    unsigned short* wte = wt + (size_t)e * K * N + (size_t)n0 * K + k0;
    int tid = threadIdx.x;

    int kg = tid >> 4;
    int nq = (tid & 15) * 4;
    float4 r0 = *(const float4*)(we + (size_t)(kg * 4 + 0) * N + nq);
    float4 r1 = *(const float4*)(we + (size_t)(kg * 4 + 1) * N + nq);
    float4 r2 = *(const float4*)(we + (size_t)(kg * 4 + 2) * N + nq);
    float4 r3 = *(const float4*)(we + (size_t)(kg * 4 + 3) * N + nq);
    ushort4 u;
    u.x = f2bf(r0.x); u.y = f2bf(r1.x); u.z = f2bf(r2.x); u.w = f2bf(r3.x);
    *(ushort4*)&tb[nq + 0][kg * 4] = u;
    u.x = f2bf(r0.y); u.y = f2bf(r1.y); u.z = f2bf(r2.y); u.w = f2bf(r3.y);
    *(ushort4*)&tb[nq + 1][kg * 4] = u;
    u.x = f2bf(r0.z); u.y = f2bf(r1.z); u.z = f2bf(r2.z); u.w = f2bf(r3.z);
    *(ushort4*)&tb[nq + 2][kg * 4] = u;
    u.x = f2bf(r0.w); u.y = f2bf(r1.w); u.z = f2bf(r2.w); u.w = f2bf(r3.w);
    *(ushort4*)&tb[nq + 3][kg * 4] = u;

    __syncthreads();

#pragma unroll
    for (int p = 0; p < 2; ++p) {
        int n = p * 32 + (tid >> 3);
        int kc = (tid & 7) * 8;
        u16x8 v = *(const u16x8*)&tb[n][kc];
        *(u16x8*)(wte + (size_t)n * K + kc) = v;
    }
}

__global__ __launch_bounds__(256) void prep_kernel(const float* __restrict__ x,
                                                   const float* __restrict__ gw,
                                                   const float* __restrict__ w1,
                                                   const float* __restrict__ w2,
                                                   int* __restrict__ cnt,
                                                   int* __restrict__ tok,
                                                   float* __restrict__ cf,
                                                   unsigned short* __restrict__ xb,
                                                   unsigned short* __restrict__ w1t,
                                                   unsigned short* __restrict__ w2t) {
    __shared__ __align__(16) unsigned short tb[64][72];
    __shared__ int ls0[TPB_G], ls1[TPB_G];
    __shared__ float lp0[TPB_G], lp1[TPB_G];
    int b = blockIdx.x;
    if (b >= GATE_BLKS) {
        int bb = b - GATE_BLKS;
        if (bb < TRW1_BLKS) trw_body(w1, w1t, D_DIM, H_DIM, bb, tb);
        else                trw_body(w2, w2t, H_DIM, D_DIM, bb - TRW1_BLKS, tb);
        return;
    }
    int tid = threadIdx.x;
    int lane = tid & 63, wv = tid >> 6;
#pragma unroll
    for (int rep = 0; rep < TPB_G / 4; ++rep) {
        int ti = rep * 4 + wv;
        int t = b * TPB_G + ti;
        const float* xr = x + (size_t)t * D_DIM;
        unsigned short* xbr = xb + (size_t)t * D_DIM;
        double acc[E_NUM];
#pragma unroll
        for (int e = 0; e < E_NUM; ++e) acc[e] = 0.0;
#pragma unroll
        for (int it = 0; it < 4; ++it) {
            int d = it * 256 + lane * 4;
            float4 v = *(const float4*)(xr + d);
            ushort4 u;
            u.x = f2bf(v.x); u.y = f2bf(v.y); u.z = f2bf(v.z); u.w = f2bf(v.w);
            *(ushort4*)(xbr + d) = u;
            const float vv[4] = {v.x, v.y, v.z, v.w};
#pragma unroll
            for (int j = 0; j < 4; ++j) {
                const float* g = gw + (size_t)(d + j) * E_NUM;
#pragma unroll
                for (int e = 0; e < E_NUM; ++e) acc[e] += (double)vv[j] * (double)g[e];
            }
        }
#pragma unroll
        for (int e = 0; e < E_NUM; ++e) {
            double v = acc[e];
#pragma unroll
            for (int off = 32; off >= 1; off >>= 1) v += __shfl_xor(v, off);
            acc[e] = v;
        }
        if (lane == 0) {
            int s0 = 0;
#pragma unroll
            for (int e = 1; e < E_NUM; ++e) if (acc[e] > acc[s0]) s0 = e;
            int s1 = -1;
#pragma unroll
            for (int e = 0; e < E_NUM; ++e) if (e != s0 && (s1 < 0 || acc[e] > acc[s1])) s1 = e;
            float l0 = (float)acc[s0], l1 = (float)acc[s1];
            float p1 = __expf(l1 - l0);
            float inv = 1.0f / (1.0f + p1);
            ls0[ti] = s0; ls1[ti] = s1;
            lp0[ti] = inv; lp1[ti] = p1 * inv;
        }
    }
    __syncthreads();
    if (tid < E_NUM) {
        int e = tid, c = 0;
#pragma unroll
        for (int i = 0; i < TPB_G; ++i) c += (ls0[i] == e) + (ls1[i] == e);
        if (c > 0) {
            int q = atomicAdd(&cnt[e * CNT_PAD], c);
            for (int i = 0; i < TPB_G; ++i) {
                int t = b * TPB_G + i;
                if (ls0[i] == e) { tok[e * CAP + q] = t; cf[e * CAP + q] = lp0[i]; ++q; }
                if (ls1[i] == e) { tok[e * CAP + q] = t; cf[e * CAP + q] = lp1[i]; ++q; }
            }
        }
    }
}

// ===== GEMMs: 256x256 tile, BK=64, 8 waves, 4 fine phases/K-tile, dbuf =====
// LDS row = 64 bf16 = 8 chunks of 16B; LDS[r][c] holds global chunk c^(r&7).
// Per K-tile: WAITV(0)+SBAR at top (loads had ~4 phases flight), then 4
// phases {ds_read quadrant / stage 2 gloads of t+1 into other buf / lgkm0 /
// setprio / 16 MFMA} separated by raw barriers. Phase order (mh,nh):
// (0,0),(0,1),(1,1),(1,0) reuses A per half and B across adjacent phases.

#define GEMM_CORE(AR, BR, AW, BW, tcur, last)                                 \
    WAITV0; SBAR;                                                             \
    /* phase 0: (mh0, nh0) */                                                 \
    LDA4(AR, 0); LDB2(BR, 0);                                                 \
    if (!(last)) { STG_A(AW, (tcur) + 1, 0); STG_B(BW, (tcur) + 1, 0); }      \
    LGKM0; MMQ(0, 0);                                                         \
    SBAR;                                                                     \
    /* phase 1: (mh0, nh1) */                                                 \
    LDB2(BR, 1);                                                              \
    if (!(last)) { STG_A(AW, (tcur) + 1, 1); STG_B(BW, (tcur) + 1, 1); }      \
    LGKM0; MMQ(0, 1);                                                         \
    SBAR;                                                                     \
    /* phase 2: (mh1, nh1) — B regs reused */                                 \
    LDA4(AR, 1);                                                              \
    if (!(last)) { STG_A(AW, (tcur) + 1, 2); STG_B(BW, (tcur) + 1, 2); }      \
    LGKM0; MMQ(1, 1);                                                         \
    SBAR;                                                                     \
    /* phase 3: (mh1, nh0) */                                                 \
    LDB2(BR, 0);                                                              \
    if (!(last)) { STG_A(AW, (tcur) + 1, 3); STG_B(BW, (tcur) + 1, 3); }      \
    LGKM0; MMQ(1, 0);

__global__ __launch_bounds__(512, 1) void gemm1_fast(const unsigned short* __restrict__ xb,
                                                     const unsigned short* __restrict__ w1t,
                                                     const float* __restrict__ b1,
                                                     const int* __restrict__ cnt,
                                                     const int* __restrict__ tok,
                                                     unsigned short* __restrict__ Hbuf) {
    __shared__ __align__(16) unsigned short As0[256][64], Bs0[256][64];
    __shared__ __align__(16) unsigned short As1[256][64], Bs1[256][64];
    __shared__ int s_tok[256];

    int tid = threadIdx.x, lane = tid & 63, wv = tid >> 6;
    int wm = wv >> 2, wn = wv & 3;              // 2x4 waves, 128x64 per wave
    int lm = lane & 15, lkq = lane >> 4;
    int srow = tid >> 3;                        // 0..63 staging row in chunk
    int schunk = ((tid & 7) ^ (srow & 7)) << 3; // pre-swizzled source chunk
    int rdc0 = ((lkq ^ (lm & 7)) << 3);         // swizzled read chunk, ks=0
    int rdc1 = (((4 + lkq) ^ (lm & 7)) << 3);   // ks=1

    int ne_[E_NUM], offs_[E_NUM], pref[E_NUM + 1];
    pref[0] = 0;
    int off = 0;
#pragma unroll
    for (int e = 0; e < E_NUM; ++e) {
        ne_[e] = cnt[e * CNT_PAD];
        offs_[e] = off; off += ne_[e];
        pref[e + 1] = pref[e] + ((ne_[e] + 255) >> 8) * 16;   // nbm(256)*16n
    }
    int T = pref[E_NUM];

    XCD_ITEMS(T)
    for (int ii = lb; ii < cntx_; ii += nbx) {
        int w = base_ + ii;
        int e = 0;
#pragma unroll
        for (int q = 0; q < E_NUM - 1; ++q) e += (w >= pref[q + 1]) ? 1 : 0;
        int local = w - pref[e];
        int bm0 = (local >> 4) * 256;
        int n0 = (local & 15) * 256;
        int ne = ne_[e];
        int offs = offs_[e];
        const unsigned short* w1e = w1t + (size_t)e * H_DIM * D_DIM;

        __syncthreads();    // prev item done; full drain
        if (tid < 256) s_tok[tid] = tok[e * CAP + min(bm0 + tid, ne - 1)];
        __syncthreads();

        const unsigned short* gA[4];
#pragma unroll
        for (int q = 0; q < 4; ++q)
            gA[q] = xb + (size_t)s_tok[q * 64 + srow] * D_DIM + schunk;
        const unsigned short* gB = w1e + (size_t)(n0 + srow) * D_DIM + schunk;

        float bias_v[4];
#pragma unroll
        for (int j = 0; j < 4; ++j)
            bias_v[j] = b1[(size_t)e * H_DIM + n0 + wn * 64 + j * 16 + lm];

        f32x4 acc[8][4];
#pragma unroll
        for (int i = 0; i < 8; ++i)
#pragma unroll
            for (int j = 0; j < 4; ++j) { f32x4 z = {0.f, 0.f, 0.f, 0.f}; acc[i][j] = z; }

        bf16x8 afr[4][2], bfr[2][2];

        auto STG_A = [&](unsigned short (&A)[256][64], int kb, int q) {
            gld_lds16(gA[q] + kb * 64, &A[q * 64 + wv * 8][0]);
        };
        auto STG_B = [&](unsigned short (&B)[256][64], int kb, int q) {
            gld_lds16(gB + (size_t)(q * 64) * D_DIM + kb * 64, &B[q * 64 + wv * 8][0]);
        };
#define LDA4(AR, mh)                                                          \
        _Pragma("unroll")                                                     \
        for (int f = 0; f < 4; ++f) {                                         \
            int row = wm * 128 + ((mh) * 4 + f) * 16 + lm;                    \
            afr[f][0] = *(const bf16x8*)&AR[row][rdc0];                       \
            afr[f][1] = *(const bf16x8*)&AR[row][rdc1];                       \
        }
#define LDB2(BR, nh)                                                          \
        _Pragma("unroll")                                                     \
        for (int j = 0; j < 2; ++j) {                                         \
            int col = wn * 64 + ((nh) * 2 + j) * 16 + lm;                     \
            bfr[j][0] = *(const bf16x8*)&BR[col][rdc0];                       \
            bfr[j][1] = *(const bf16x8*)&BR[col][rdc1];                       \
        }
#define MMQ(mh, nh)                                                           \
        __builtin_amdgcn_s_setprio(1);                                        \
        _Pragma("unroll")                                                     \
        for (int f = 0; f < 4; ++f)                                           \
            _Pragma("unroll")                                                 \
            for (int j = 0; j < 2; ++j) {                                     \
                acc[(mh) * 4 + f][(nh) * 2 + j] =                             \
                    __builtin_amdgcn_mfma_f32_16x16x32_bf16(                  \
                        afr[f][0], bfr[j][0], acc[(mh) * 4 + f][(nh) * 2 + j], 0, 0, 0); \
                acc[(mh) * 4 + f][(nh) * 2 + j] =                             \
                    __builtin_amdgcn_mfma_f32_16x16x32_bf16(                  \
                        afr[f][1], bfr[j][1], acc[(mh) * 4 + f][(nh) * 2 + j], 0, 0, 0); \
            }                                                                 \
        __builtin_amdgcn_s_setprio(0);

        const int NT = D_DIM / 64;   // 16 (even)
#pragma unroll
        for (int q = 0; q < 4; ++q) { STG_A(As0, 0, q); STG_B(Bs0, 0, q); }
        for (int t = 0; t < NT; t += 2) {
            GEMM_CORE(As0, Bs0, As1, Bs1, t, false)
            GEMM_CORE(As1, Bs1, As0, Bs0, t + 1, (t + 2 >= NT))
        }
#undef LDA4
#undef LDB2
#undef MMQ

#pragma unroll
        for (int i = 0; i < 8; ++i) {
#pragma unroll
            for (int r = 0; r < 4; ++r) {
                int row = wm * 128 + i * 16 + lkq * 4 + r;
                int gr = bm0 + row;
                if (gr >= ne) continue;
                size_t rb = (size_t)(offs + gr) * H_DIM;
#pragma unroll
                for (int j = 0; j < 4; ++j) {
                    int gn = n0 + wn * 64 + j * 16 + lm;
                    float v = acc[i][j][r] + bias_v[j];
                    Hbuf[rb + gn] = f2bf(gelu_sig(v));
                }
            }
        }
    }
}

__global__ __launch_bounds__(512, 1) void gemm2_fast(const unsigned short* __restrict__ Hbuf,
                                                     const unsigned short* __restrict__ w2t,
                                                     const float* __restrict__ b2,
                                                     const int* __restrict__ cnt,
                                                     const int* __restrict__ tok,
                                                     const float* __restrict__ cf,
                                                     float* __restrict__ out) {
    __shared__ __align__(16) unsigned short As0[256][64], Bs0[256][64];
    __shared__ __align__(16) unsigned short As1[256][64], Bs1[256][64];
    __shared__ int s_tok[256];
    __shared__ float s_cf[256];

    int tid = threadIdx.x, lane = tid & 63, wv = tid >> 6;
    int wm = wv >> 2, wn = wv & 3;
    int lm = lane & 15, lkq = lane >> 4;
    int srow = tid >> 3;
    int schunk = ((tid & 7) ^ (srow & 7)) << 3;
    int rdc0 = ((lkq ^ (lm & 7)) << 3);
    int rdc1 = (((4 + lkq) ^ (lm & 7)) << 3);

    int ne_[E_NUM], offs_[E_NUM], pref[E_NUM + 1];
    pref[0] = 0;
    int off = 0;
#pragma unroll
    for (int e = 0; e < E_NUM; ++e) {
        ne_[e] = cnt[e * CNT_PAD];
        offs_[e] = off; off += ne_[e];
        pref[e + 1] = pref[e] + ((ne_[e] + 255) >> 8) * 4;    // nbm(256)*4n
    }
    int T = pref[E_NUM];

    XCD_ITEMS(T)
    for (int ii = lb; ii < cntx_; ii += nbx) {
        int w = base_ + ii;
        int e = 0;
#pragma unroll
        for (int q = 0; q < E_NUM - 1; ++q) e += (w >= pref[q + 1]) ? 1 : 0;
        int local = w - pref[e];
        int bm0 = (local >> 2) * 256;
        int n0 = (local & 3) * 256;
        int ne = ne_[e];
        int offs = offs_[e];
        const unsigned short* w2e = w2t + (size_t)e * H_DIM * D_DIM;

        __syncthreads();
        if (tid < 256) {
            int gi = min(bm0 + tid, ne - 1);
            s_tok[tid] = tok[e * CAP + gi];
            s_cf[tid] = cf[e * CAP + gi];
        }
        __syncthreads();

        const unsigned short* gA[4];
#pragma unroll
        for (int q = 0; q < 4; ++q)
            gA[q] = Hbuf + (size_t)(offs + min(bm0 + q * 64 + srow, ne - 1)) * H_DIM + schunk;
        const unsigned short* gB = w2e + (size_t)(n0 + srow) * H_DIM + schunk;

        float bias_v[4];
#pragma unroll
        for (int j = 0; j < 4; ++j)
            bias_v[j] = b2[(size_t)e * D_DIM + n0 + wn * 64 + j * 16 + lm];

        f32x4 acc[8][4];
#pragma unroll
        for (int i = 0; i < 8; ++i)
#pragma unroll
            for (int j = 0; j < 4; ++j) { f32x4 z = {0.f, 0.f, 0.f, 0.f}; acc[i][j] = z; }

        bf16x8 afr[4][2], bfr[2][2];

        auto STG_A = [&](unsigned short (&A)[256][64], int kb, int q) {
            gld_lds16(gA[q] + kb * 64, &A[q * 64 + wv * 8][0]);
        };
        auto STG_B = [&](unsigned short (&B)[256][64], int kb, int q) {
            gld_lds16(gB + (size_t)(q * 64) * H_DIM + kb * 64, &B[q * 64 + wv * 8][0]);
        };
#define LDA4(AR, mh)                                                          \
        _Pragma("unroll")                                                     \
        for (int f = 0; f < 4; ++f) {                                         \
            int row = wm * 128 + ((mh) * 4 + f) * 16 + lm;                    \
            afr[f][0] = *(const bf16x8*)&AR[row][rdc0];                       \
            afr[f][1] = *(const bf16x8*)&AR[row][rdc1];                       \
        }
#define LDB2(BR, nh)                                                          \
        _Pragma("unroll")                                                     \
        for (int j = 0; j < 2; ++j) {                                         \
            int col = wn * 64 + ((nh) * 2 + j) * 16 + lm;                     \
            bfr[j][0] = *(const bf16x8*)&BR[col][rdc0];                       \
            bfr[j][1] = *(const bf16x8*)&BR[col][rdc1];                       \
        }
#define MMQ(mh, nh)                                                           \
        __builtin_amdgcn_s_setprio(1);                                        \
        _Pragma("unroll")                                                     \
        for (int f = 0; f < 4; ++f)                                           \
            _Pragma("unroll")                                                 \
            for (int j = 0; j < 2; ++j) {                                     \
                acc[(mh) * 4 + f][(nh) * 2 + j] =                             \
                    __builtin_amdgcn_mfma_f32_16x16x32_bf16(                  \
                        afr[f][0], bfr[j][0], acc[(mh) * 4 + f][(nh) * 2 + j], 0, 0, 0); \
                acc[(mh) * 4 + f][(nh) * 2 + j] =                             \
                    __builtin_amdgcn_mfma_f32_16x16x32_bf16(                  \
                        afr[f][1], bfr[j][1], acc[(mh) * 4 + f][(nh) * 2 + j], 0, 0, 0); \
            }                                                                 \
        __builtin_amdgcn_s_setprio(0);

        const int NT = H_DIM / 64;   // 64 (even)
#pragma unroll
        for (int q = 0; q < 4; ++q) { STG_A(As0, 0, q); STG_B(Bs0, 0, q); }
        for (int t = 0; t < NT; t += 2) {
            GEMM_CORE(As0, Bs0, As1, Bs1, t, false)
            GEMM_CORE(As1, Bs1, As0, Bs0, t + 1, (t + 2 >= NT))
        }
#undef LDA4
#undef LDB2
#undef MMQ

#pragma unroll
        for (int i = 0; i < 8; ++i) {
#pragma unroll
            for (int r = 0; r < 4; ++r) {
                int row = wm * 128 + i * 16 + lkq * 4 + r;
                int gr = bm0 + row;
                if (gr >= ne) continue;
                int tk = s_tok[row];
                float cw = s_cf[row];
#pragma unroll
                for (int j = 0; j < 4; ++j) {
                    int gn = n0 + wn * 64 + j * 16 + lm;
                    float y = acc[i][j][r] + bias_v[j];
                    atomicAdd(&out[(size_t)tk * D_DIM + gn], cw * y);
                }
            }
        }
    }
}

extern "C" void kernel_launch(void* const* d_in, const int* in_sizes, int n_in,
                              void* d_out, int out_size, void* d_ws, size_t ws_size,
                              hipStream_t stream) {
    const float* x  = (const float*)d_in[0];
    const float* gw = (const float*)d_in[1];
    const float* w1 = (const float*)d_in[2];
    const float* b1 = (const float*)d_in[3];
    const float* w2 = (const float*)d_in[4];
    const float* b2 = (const float*)d_in[5];
    float* out = (float*)d_out;

    char* ws = (char*)d_ws;
    const size_t SZ_CNT   = E_NUM * CNT_PAD * 4;
    const size_t SZ_ROUTE = SZ_CNT + (size_t)2 * E_NUM * CAP * 4;
    const size_t SZ_XB    = (size_t)T_TOKENS * D_DIM * 2;
    const size_t SZ_W     = (size_t)E_NUM * D_DIM * H_DIM * 2;
    const size_t SZ_H     = (size_t)2 * T_TOKENS * H_DIM * 2;

    int*   cnt = (int*)ws;
    int*   tok = (int*)(ws + SZ_CNT);
    float* cff = (float*)(ws + SZ_CNT + E_NUM * CAP * 4);

    size_t need_fast = SZ_ROUTE + SZ_XB + 2 * SZ_W + SZ_H;
    if (ws_size < need_fast) return;  // loud failure: out stays poisoned

    unsigned short* xb   = (unsigned short*)(ws + SZ_ROUTE);
    unsigned short* w1t  = (unsigned short*)(ws + SZ_ROUTE + SZ_XB);
    unsigned short* w2t  = (unsigned short*)(ws + SZ_ROUTE + SZ_XB + SZ_W);
    unsigned short* Hbuf = (unsigned short*)(ws + SZ_ROUTE + SZ_XB + 2 * SZ_W);

    hipMemsetAsync(cnt, 0, SZ_CNT, stream);
    hipMemsetAsync(out, 0, (size_t)out_size * sizeof(float), stream);

    prep_kernel<<<GATE_BLKS + TRW1_BLKS + TRW2_BLKS, 256, 0, stream>>>(
        x, gw, w1, w2, cnt, tok, cff, xb, w1t, w2t);

    gemm1_fast<<<256, 512, 0, stream>>>(xb, w1t, b1, cnt, tok, Hbuf);
    gemm2_fast<<<256, 512, 0, stream>>>(Hbuf, w2t, b2, cnt, tok, cff, out);
}

// Round 17
// 556.291 us; speedup vs baseline: 1.1154x; 1.1154x over previous
//
#include <hip/hip_runtime.h>
#include <hip/hip_bf16.h>

#define T_TOKENS 8192
#define D_DIM 1024
#define H_DIM 4096
#define E_NUM 8
#define CAP 8192
#define CNT_PAD 16

#define TPB_G 32
#define GATE_BLKS (T_TOKENS / TPB_G)
#define TRW1_BLKS ((D_DIM / 64) * (H_DIM / 64) * E_NUM)
#define TRW2_BLKS ((H_DIM / 64) * (D_DIM / 64) * E_NUM)

typedef short bf16x8 __attribute__((ext_vector_type(8)));
typedef float f32x4 __attribute__((ext_vector_type(4)));
typedef unsigned short u16x8 __attribute__((ext_vector_type(8)));

__device__ inline unsigned short f2bf(float f) {
    __hip_bfloat16 h = __float2bfloat16(f);
    return *reinterpret_cast<unsigned short*>(&h);
}

__device__ inline float gelu_sig(float v) {
    float x = v * (1.5957691216057308f + 0.07135481627f * v * v);
    return v * __builtin_amdgcn_rcpf(1.0f + __expf(-x));
}

__device__ inline void gld_lds16(const unsigned short* g, unsigned short* lds) {
    __builtin_amdgcn_global_load_lds(
        (const __attribute__((address_space(1))) void*)g,
        (__attribute__((address_space(3))) void*)lds, 16, 0, 0);
}

#define WAITV0 do { asm volatile("s_waitcnt vmcnt(0)" ::: "memory"); \
                    __builtin_amdgcn_sched_barrier(0); } while (0)
#define SBAR   do { __builtin_amdgcn_sched_barrier(0); \
                    __builtin_amdgcn_s_barrier(); \
                    __builtin_amdgcn_sched_barrier(0); } while (0)

// XCD-chunked bijective item mapping (m204)
#define XCD_ITEMS(T)                                                          \
    int xcd = blockIdx.x & 7;                                                 \
    int lb  = blockIdx.x >> 3;                                                \
    int nbx = gridDim.x >> 3;                                                 \
    int q_ = (T) >> 3, r_ = (T) & 7;                                          \
    int base_ = (xcd < r_) ? xcd * (q_ + 1) : r_ * (q_ + 1) + (xcd - r_) * q_;\
    int cntx_ = (xcd < r_) ? q_ + 1 : q_;

// ---------------- fused prepass: gate(+x cvt) | trw(w1) | trw(w2) ----------
__device__ inline void trw_body(const float* __restrict__ w,
                                unsigned short* __restrict__ wt,
                                int K, int N, int bb,
                                unsigned short (*tb)[72]) {
    int nk = K / 64, nn = N / 64;
    int e = bb / (nk * nn);
    int rem = bb - e * (nk * nn);
    int k0 = (rem % nk) * 64;
    int n0 = (rem / nk) * 64;
    const float* we = w + (size_t)e * K * N + (size_t)k0 * N + n0;
    unsigned short* wte = wt + (size_t)e * K * N + (size_t)n0 * K + k0;
    int tid = threadIdx.x;

    int kg = tid >> 4;
    int nq = (tid & 15) * 4;
    float4 r0 = *(const float4*)(we + (size_t)(kg * 4 + 0) * N + nq);
    float4 r1 = *(const float4*)(we + (size_t)(kg * 4 + 1) * N + nq);
    float4 r2 = *(const float4*)(we + (size_t)(kg * 4 + 2) * N + nq);
    float4 r3 = *(const float4*)(we + (size_t)(kg * 4 + 3) * N + nq);
    ushort4 u;
    u.x = f2bf(r0.x); u.y = f2bf(r1.x); u.z = f2bf(r2.x); u.w = f2bf(r3.x);
    *(ushort4*)&tb[nq + 0][kg * 4] = u;
    u.x = f2bf(r0.y); u.y = f2bf(r1.y); u.z = f2bf(r2.y); u.w = f2bf(r3.y);
    *(ushort4*)&tb[nq + 1][kg * 4] = u;
    u.x = f2bf(r0.z); u.y = f2bf(r1.z); u.z = f2bf(r2.z); u.w = f2bf(r3.z);
    *(ushort4*)&tb[nq + 2][kg * 4] = u;
    u.x = f2bf(r0.w); u.y = f2bf(r1.w); u.z = f2bf(r2.w); u.w = f2bf(r3.w);
    *(ushort4*)&tb[nq + 3][kg * 4] = u;

    __syncthreads();

#pragma unroll
    for (int p = 0; p < 2; ++p) {
        int n = p * 32 + (tid >> 3);
        int kc = (tid & 7) * 8;
        u16x8 v = *(const u16x8*)&tb[n][kc];
        *(u16x8*)(wte + (size_t)n * K + kc) = v;
    }
}

__global__ __launch_bounds__(256) void prep_kernel(const float* __restrict__ x,
                                                   const float* __restrict__ gw,
                                                   const float* __restrict__ w1,
                                                   const float* __restrict__ w2,
                                                   int* __restrict__ cnt,
                                                   int* __restrict__ tok,
                                                   float* __restrict__ cf,
                                                   unsigned short* __restrict__ xb,
                                                   unsigned short* __restrict__ w1t,
                                                   unsigned short* __restrict__ w2t) {
    __shared__ __align__(16) unsigned short tb[64][72];
    __shared__ int ls0[TPB_G], ls1[TPB_G];
    __shared__ float lp0[TPB_G], lp1[TPB_G];
    int b = blockIdx.x;
    if (b >= GATE_BLKS) {
        int bb = b - GATE_BLKS;
        if (bb < TRW1_BLKS) trw_body(w1, w1t, D_DIM, H_DIM, bb, tb);
        else                trw_body(w2, w2t, H_DIM, D_DIM, bb - TRW1_BLKS, tb);
        return;
    }
    int tid = threadIdx.x;
    int lane = tid & 63, wv = tid >> 6;
#pragma unroll
    for (int rep = 0; rep < TPB_G / 4; ++rep) {
        int ti = rep * 4 + wv;
        int t = b * TPB_G + ti;
        const float* xr = x + (size_t)t * D_DIM;
        unsigned short* xbr = xb + (size_t)t * D_DIM;
        double acc[E_NUM];
#pragma unroll
        for (int e = 0; e < E_NUM; ++e) acc[e] = 0.0;
#pragma unroll
        for (int it = 0; it < 4; ++it) {
            int d = it * 256 + lane * 4;
            float4 v = *(const float4*)(xr + d);
            ushort4 u;
            u.x = f2bf(v.x); u.y = f2bf(v.y); u.z = f2bf(v.z); u.w = f2bf(v.w);
            *(ushort4*)(xbr + d) = u;
            const float vv[4] = {v.x, v.y, v.z, v.w};
#pragma unroll
            for (int j = 0; j < 4; ++j) {
                const float* g = gw + (size_t)(d + j) * E_NUM;
#pragma unroll
                for (int e = 0; e < E_NUM; ++e) acc[e] += (double)vv[j] * (double)g[e];
            }
        }
#pragma unroll
        for (int e = 0; e < E_NUM; ++e) {
            double v = acc[e];
#pragma unroll
            for (int off = 32; off >= 1; off >>= 1) v += __shfl_xor(v, off);
            acc[e] = v;
        }
        if (lane == 0) {
            int s0 = 0;
#pragma unroll
            for (int e = 1; e < E_NUM; ++e) if (acc[e] > acc[s0]) s0 = e;
            int s1 = -1;
#pragma unroll
            for (int e = 0; e < E_NUM; ++e) if (e != s0 && (s1 < 0 || acc[e] > acc[s1])) s1 = e;
            float l0 = (float)acc[s0], l1 = (float)acc[s1];
            float p1 = __expf(l1 - l0);
            float inv = 1.0f / (1.0f + p1);
            ls0[ti] = s0; ls1[ti] = s1;
            lp0[ti] = inv; lp1[ti] = p1 * inv;
        }
    }
    __syncthreads();
    if (tid < E_NUM) {
        int e = tid, c = 0;
#pragma unroll
        for (int i = 0; i < TPB_G; ++i) c += (ls0[i] == e) + (ls1[i] == e);
        if (c > 0) {
            int q = atomicAdd(&cnt[e * CNT_PAD], c);
            for (int i = 0; i < TPB_G; ++i) {
                int t = b * TPB_G + i;
                // tok encodes 2*token + slot (slot 0 = top-1 expert)
                if (ls0[i] == e) { tok[e * CAP + q] = t * 2;     cf[e * CAP + q] = lp0[i]; ++q; }
                if (ls1[i] == e) { tok[e * CAP + q] = t * 2 + 1; cf[e * CAP + q] = lp1[i]; ++q; }
            }
        }
    }
}

// ================= GEMM1: 128x128 tile, BK=64, XCD-chunked flat items ======
// LDS row = 64 bf16 = 8 chunks of 16B; LDS[r][c] holds global chunk c^(r&7).
__global__ __launch_bounds__(256, 2) void gemm1_fast(const unsigned short* __restrict__ xb,
                                                     const unsigned short* __restrict__ w1t,
                                                     const float* __restrict__ b1,
                                                     const int* __restrict__ cnt,
                                                     const int* __restrict__ tok,
                                                     unsigned short* __restrict__ Hbuf) {
    __shared__ __align__(16) unsigned short As0[128][64], As1[128][64];
    __shared__ __align__(16) unsigned short Bs0[128][64], Bs1[128][64];
    __shared__ int s_tok[128];

    int tid = threadIdx.x, lane = tid & 63, wv = tid >> 6;
    int wr = (wv >> 1) * 64, wc = (wv & 1) * 64;
    int lm = lane & 15, lk = lane >> 4;
    int srow = lane >> 3;
    int schunk = ((lane & 7) ^ srow) << 3;

    int ne_[E_NUM], offs_[E_NUM], pref[E_NUM + 1];
    pref[0] = 0;
    int off = 0;
#pragma unroll
    for (int e = 0; e < E_NUM; ++e) {
        ne_[e] = cnt[e * CNT_PAD];
        offs_[e] = off; off += ne_[e];
        pref[e + 1] = pref[e] + ((ne_[e] + 127) >> 7) * 32;
    }
    int T = pref[E_NUM];

    XCD_ITEMS(T)
    for (int ii = lb; ii < cntx_; ii += nbx) {
        int w = base_ + ii;
        int e = 0;
#pragma unroll
        for (int q = 0; q < E_NUM - 1; ++q) e += (w >= pref[q + 1]) ? 1 : 0;
        int local = w - pref[e];
        int bm0 = (local >> 5) * 128;
        int n0 = (local & 31) * 128;
        int ne = ne_[e];
        int offs = offs_[e];
        const unsigned short* w1e = w1t + (size_t)e * H_DIM * D_DIM;

        __syncthreads();
        if (tid < 128) s_tok[tid] = tok[e * CAP + min(bm0 + tid, ne - 1)] >> 1;  // decode token
        __syncthreads();

        const unsigned short* gA[4];
        const unsigned short* gB[4];
#pragma unroll
        for (int l = 0; l < 4; ++l) {
            gA[l] = xb + (size_t)s_tok[wv * 32 + l * 8 + srow] * D_DIM + schunk;
            gB[l] = w1e + (size_t)(n0 + wv * 32 + l * 8 + srow) * D_DIM + schunk;
        }
        float bias_v[4];
#pragma unroll
        for (int j = 0; j < 4; ++j) bias_v[j] = b1[(size_t)e * H_DIM + n0 + wc + j * 16 + lm];

        f32x4 acc[4][4];
#pragma unroll
        for (int i = 0; i < 4; ++i)
#pragma unroll
            for (int j = 0; j < 4; ++j) { f32x4 z = {0.f, 0.f, 0.f, 0.f}; acc[i][j] = z; }

        auto STAGE = [&](unsigned short (&A)[128][64], unsigned short (&B)[128][64], int kb) {
            int k0 = kb * 64;
#pragma unroll
            for (int l = 0; l < 4; ++l) gld_lds16(gA[l] + k0, &A[wv * 32 + l * 8][0]);
#pragma unroll
            for (int l = 0; l < 4; ++l) gld_lds16(gB[l] + k0, &B[wv * 32 + l * 8][0]);
        };
        auto COMPUTE = [&](unsigned short (&A)[128][64], unsigned short (&B)[128][64]) {
#pragma unroll
            for (int ks = 0; ks < 2; ++ks) {
                bf16x8 a[4], b[4];
                int c = (((ks * 4 + lk) ^ (lm & 7)) << 3);
#pragma unroll
                for (int f = 0; f < 4; ++f) a[f] = *(const bf16x8*)&A[wr + f * 16 + lm][c];
#pragma unroll
                for (int f = 0; f < 4; ++f) b[f] = *(const bf16x8*)&B[wc + f * 16 + lm][c];
                __builtin_amdgcn_s_setprio(1);
#pragma unroll
                for (int i = 0; i < 4; ++i)
#pragma unroll
                    for (int j = 0; j < 4; ++j)
                        acc[i][j] = __builtin_amdgcn_mfma_f32_16x16x32_bf16(a[i], b[j], acc[i][j], 0, 0, 0);
                __builtin_amdgcn_s_setprio(0);
            }
        };

        const int NT = D_DIM / 64;   // 16
        STAGE(As0, Bs0, 0);
        WAITV0; SBAR;
        for (int t = 0; t < NT; t += 2) {
            if (t + 1 < NT) STAGE(As1, Bs1, t + 1);
            COMPUTE(As0, Bs0);
            WAITV0; SBAR;
            if (t + 2 < NT) STAGE(As0, Bs0, t + 2);
            COMPUTE(As1, Bs1);
            WAITV0; SBAR;
        }

#pragma unroll
        for (int i = 0; i < 4; ++i) {
#pragma unroll
            for (int r = 0; r < 4; ++r) {
                int row = wr + i * 16 + lk * 4 + r;
                int gr = bm0 + row;
                if (gr >= ne) continue;
                size_t rb = (size_t)(offs + gr) * H_DIM;
#pragma unroll
                for (int j = 0; j < 4; ++j) {
                    int gn = n0 + wc + j * 16 + lm;
                    float v = acc[i][j][r] + bias_v[j];
                    Hbuf[rb + gn] = f2bf(gelu_sig(v));
                }
            }
        }
    }
}

// ====== GEMM2: 128x128 tile, BK=64, 2 blk/CU; non-atomic Ypart epilogue ====
__global__ __launch_bounds__(256, 2) void gemm2_fast(const unsigned short* __restrict__ Hbuf,
                                                     const unsigned short* __restrict__ w2t,
                                                     const float* __restrict__ b2,
                                                     const int* __restrict__ cnt,
                                                     const int* __restrict__ tok,
                                                     const float* __restrict__ cf,
                                                     float* __restrict__ ypart) {
    __shared__ __align__(16) unsigned short As0[128][64], As1[128][64];
    __shared__ __align__(16) unsigned short Bs0[128][64], Bs1[128][64];
    __shared__ int s_tok[128];
    __shared__ float s_cf[128];

    int tid = threadIdx.x, lane = tid & 63, wv = tid >> 6;
    int wr = (wv >> 1) * 64, wc = (wv & 1) * 64;
    int lm = lane & 15, lk = lane >> 4;
    int srow = lane >> 3;
    int schunk = ((lane & 7) ^ srow) << 3;

    int ne_[E_NUM], offs_[E_NUM], pref[E_NUM + 1];
    pref[0] = 0;
    int off = 0;
#pragma unroll
    for (int e = 0; e < E_NUM; ++e) {
        ne_[e] = cnt[e * CNT_PAD];
        offs_[e] = off; off += ne_[e];
        pref[e + 1] = pref[e] + ((ne_[e] + 127) >> 7) * 8;   // nbm * 8 n-tiles
    }
    int T = pref[E_NUM];

    XCD_ITEMS(T)
    for (int ii = lb; ii < cntx_; ii += nbx) {
        int w = base_ + ii;
        int e = 0;
#pragma unroll
        for (int q = 0; q < E_NUM - 1; ++q) e += (w >= pref[q + 1]) ? 1 : 0;
        int local = w - pref[e];
        int bm0 = (local >> 3) * 128;
        int n0 = (local & 7) * 128;
        int ne = ne_[e];
        int offs = offs_[e];
        const unsigned short* w2e = w2t + (size_t)e * H_DIM * D_DIM;

        __syncthreads();
        if (tid < 128) {
            int gi = min(bm0 + tid, ne - 1);
            s_tok[tid] = tok[e * CAP + gi];
            s_cf[tid] = cf[e * CAP + gi];
        }
        __syncthreads();

        const unsigned short* gA[4];
        const unsigned short* gB[4];
#pragma unroll
        for (int l = 0; l < 4; ++l) {
            gA[l] = Hbuf + (size_t)(offs + min(bm0 + wv * 32 + l * 8 + srow, ne - 1)) * H_DIM + schunk;
            gB[l] = w2e + (size_t)(n0 + wv * 32 + l * 8 + srow) * H_DIM + schunk;
        }
        float bias_v[4];
#pragma unroll
        for (int j = 0; j < 4; ++j) bias_v[j] = b2[(size_t)e * D_DIM + n0 + wc + j * 16 + lm];

        f32x4 acc[4][4];
#pragma unroll
        for (int i = 0; i < 4; ++i)
#pragma unroll
            for (int j = 0; j < 4; ++j) { f32x4 z = {0.f, 0.f, 0.f, 0.f}; acc[i][j] = z; }

        auto STAGE = [&](unsigned short (&A)[128][64], unsigned short (&B)[128][64], int kb) {
            int k0 = kb * 64;
#pragma unroll
            for (int l = 0; l < 4; ++l) gld_lds16(gA[l] + k0, &A[wv * 32 + l * 8][0]);
#pragma unroll
            for (int l = 0; l < 4; ++l) gld_lds16(gB[l] + k0, &B[wv * 32 + l * 8][0]);
        };
        auto COMPUTE = [&](unsigned short (&A)[128][64], unsigned short (&B)[128][64]) {
#pragma unroll
            for (int ks = 0; ks < 2; ++ks) {
                bf16x8 a[4], b[4];
                int c = (((ks * 4 + lk) ^ (lm & 7)) << 3);
#pragma unroll
                for (int f = 0; f < 4; ++f) a[f] = *(const bf16x8*)&A[wr + f * 16 + lm][c];
#pragma unroll
                for (int f = 0; f < 4; ++f) b[f] = *(const bf16x8*)&B[wc + f * 16 + lm][c];
                __builtin_amdgcn_s_setprio(1);
#pragma unroll
                for (int i = 0; i < 4; ++i)
#pragma unroll
                    for (int j = 0; j < 4; ++j)
                        acc[i][j] = __builtin_amdgcn_mfma_f32_16x16x32_bf16(a[i], b[j], acc[i][j], 0, 0, 0);
                __builtin_amdgcn_s_setprio(0);
            }
        };

        const int NT = H_DIM / 64;   // 64
        STAGE(As0, Bs0, 0);
        WAITV0; SBAR;
        for (int t = 0; t < NT; t += 2) {
            if (t + 1 < NT) STAGE(As1, Bs1, t + 1);
            COMPUTE(As0, Bs0);
            WAITV0; SBAR;
            if (t + 2 < NT) STAGE(As0, Bs0, t + 2);
            COMPUTE(As1, Bs1);
            WAITV0; SBAR;
        }

#pragma unroll
        for (int i = 0; i < 4; ++i) {
#pragma unroll
            for (int r = 0; r < 4; ++r) {
                int row = wr + i * 16 + lk * 4 + r;
                int gr = bm0 + row;
                if (gr >= ne) continue;
                int tk = s_tok[row];
                float cw = s_cf[row];
                // non-atomic: (token, slot) is unique per routed row
                float* yrow = ypart + ((size_t)(tk & 1) * T_TOKENS + (tk >> 1)) * D_DIM;
#pragma unroll
                for (int j = 0; j < 4; ++j) {
                    int gn = n0 + wc + j * 16 + lm;
                    float y = acc[i][j][r] + bias_v[j];
                    yrow[gn] = cw * y;
                }
            }
        }
    }
}

// ---------------- combine: out = Ypart[0] + Ypart[1] -----------------------
__global__ __launch_bounds__(256) void combine_kernel(const float* __restrict__ yp,
                                                      float* __restrict__ out) {
    size_t i = ((size_t)blockIdx.x * 256 + threadIdx.x) * 4;
    const size_t TD = (size_t)T_TOKENS * D_DIM;
    float4 a = *(const float4*)(yp + i);
    float4 b = *(const float4*)(yp + TD + i);
    float4 o;
    o.x = a.x + b.x; o.y = a.y + b.y; o.z = a.z + b.z; o.w = a.w + b.w;
    *(float4*)(out + i) = o;
}

extern "C" void kernel_launch(void* const* d_in, const int* in_sizes, int n_in,
                              void* d_out, int out_size, void* d_ws, size_t ws_size,
                              hipStream_t stream) {
    const float* x  = (const float*)d_in[0];
    const float* gw = (const float*)d_in[1];
    const float* w1 = (const float*)d_in[2];
    const float* b1 = (const float*)d_in[3];
    const float* w2 = (const float*)d_in[4];
    const float* b2 = (const float*)d_in[5];
    float* out = (float*)d_out;

    char* ws = (char*)d_ws;
    const size_t SZ_CNT   = E_NUM * CNT_PAD * 4;
    const size_t SZ_ROUTE = SZ_CNT + (size_t)2 * E_NUM * CAP * 4;
    const size_t SZ_XB    = (size_t)T_TOKENS * D_DIM * 2;
    const size_t SZ_W     = (size_t)E_NUM * D_DIM * H_DIM * 2;   // 67.1 MB
    const size_t SZ_H     = (size_t)2 * T_TOKENS * H_DIM * 2;

    int*   cnt = (int*)ws;
    int*   tok = (int*)(ws + SZ_CNT);
    float* cff = (float*)(ws + SZ_CNT + E_NUM * CAP * 4);

    size_t need_fast = SZ_ROUTE + SZ_XB + 2 * SZ_W + SZ_H;
    if (ws_size < need_fast) return;  // loud failure: out stays poisoned

    unsigned short* xb   = (unsigned short*)(ws + SZ_ROUTE);
    unsigned short* w1t  = (unsigned short*)(ws + SZ_ROUTE + SZ_XB);
    unsigned short* w2t  = (unsigned short*)(ws + SZ_ROUTE + SZ_XB + SZ_W);
    unsigned short* Hbuf = (unsigned short*)(ws + SZ_ROUTE + SZ_XB + 2 * SZ_W);
    // Ypart aliases w1t: 2*T*D*4 = 67.1 MB = SZ_W; w1t is dead after gemm1.
    float* ypart = (float*)w1t;

    hipMemsetAsync(cnt, 0, SZ_CNT, stream);

    prep_kernel<<<GATE_BLKS + TRW1_BLKS + TRW2_BLKS, 256, 0, stream>>>(
        x, gw, w1, w2, cnt, tok, cff, xb, w1t, w2t);

    gemm1_fast<<<512, 256, 0, stream>>>(xb, w1t, b1, cnt, tok, Hbuf);
    gemm2_fast<<<512, 256, 0, stream>>>(Hbuf, w2t, b2, cnt, tok, cff, ypart);
    combine_kernel<<<(T_TOKENS * D_DIM) / (256 * 4), 256, 0, stream>>>(ypart, out);
}